// Round 3
// baseline (1182.876 us; speedup 1.0000x reference)
//
#include <hip/hip_runtime.h>

#define CIN   256
#define COUT  512
#define HW    1024     // H*W = 32*32
#define ITERS 20

typedef __attribute__((ext_vector_type(8)))  short bf16x8;
typedef __attribute__((ext_vector_type(4)))  float f32x4;
typedef __attribute__((ext_vector_type(16))) float f32x16;
typedef __attribute__((ext_vector_type(2)))  unsigned u32x2;

__device__ __forceinline__ unsigned short f2b(float x) {
  unsigned b = __builtin_bit_cast(unsigned, x);
  unsigned r = (b + 0x7FFFu + ((b >> 16) & 1u)) >> 16;   // RNE
  return (unsigned short)r;
}
// packed f32x2 -> bf16x2 (RNE), lo = a, hi = b
__device__ __forceinline__ unsigned cvt_pk_bf16(float a, float b) {
  unsigned r;
  asm("v_cvt_pk_bf16_f32 %0, %1, %2" : "=v"(r) : "v"(a), "v"(b));
  return r;
}

// 32x32x16 MFMA fragment conventions (gfx950):
//  A-frag: lane l holds row m = l&31,  k = (l>>5)*8 + i  (i=0..7)
//  B-frag: lane l holds col n = l&31,  k = (l>>5)*8 + i
//  C/D   : col = lane&31, row = (r&3) + 8*(r>>2) + 4*(lane>>5), r in [0,16)
//
// Both GEMMs computed TRANSPOSED (A = weights, B = h/y, cols = pixels) so the
// per-lane C rows are consecutive channel indices -> packed b64 LDS restaging.
//
// w1: GEMM1 A-frags [ct:8][kt:32][lane:64][i:8];  c = ct*32+(l&31), j = kt*16+(l>>5)*8+i
// w2: GEMM2 A-frags [jt:16][kt:16][lane:64][i:8]; j = jt*32+(l&31), c = kt*16+(l>>5)*8+i
__global__ __launch_bounds__(256) void prep_weights(const float* __restrict__ w,
                                                    unsigned short* __restrict__ w1,
                                                    unsigned short* __restrict__ w2) {
  int f = blockIdx.x * 256 + threadIdx.x;   // [0, 131072)
  {
    int i = f & 7, l = (f >> 3) & 63, kt = (f >> 9) & 31, ct = f >> 14;
    int c = ct * 32 + (l & 31);
    int j = kt * 16 + ((l >> 5) << 3) + i;
    w1[f] = f2b(w[j * CIN + c]);
  }
  {
    int i = f & 7, l = (f >> 3) & 63, kt = (f >> 9) & 15, jt = f >> 13;
    int j = jt * 32 + (l & 31);
    int c = kt * 16 + ((l >> 5) << 3) + i;
    w2[f] = f2b(w[j * CIN + c]);
  }
}

// 1 WG = 32 pixels of one image, 4 waves, all 20 iterations on-chip.
// R2 post-mortem: reported VGPR is arch-VGPR only; unified budget = VGPR+AGPR.
// (256,2) forced 128+128=256 and still spilled ~95MB scratch (peak liveness ~250).
// R3: split both GEMMs into sequential halves (acc1 16, acc2 32 live) -> peak ~160,
// and let the allocator pick occupancy (no min-wave force; R1 showed forcing = spill).
// LDS 48.6KB allows 3 blocks/CU if total regs land <= 170.
__global__ __launch_bounds__(256) void nnmf_kernel(const float* __restrict__ xin,
                                                   const unsigned short* __restrict__ w1,
                                                   const unsigned short* __restrict__ w2,
                                                   float* __restrict__ out) {
  __shared__ __align__(16) unsigned short hA[32 * 512]; // 32KB  B-frags GEMM1 (k=j)
  __shared__ __align__(16) unsigned short yF[16 * 512]; // 16KB  B-frags GEMM2 (k=c)
  __shared__ __align__(16) float red[32 * 4];           // 512B  per-pixel partial sums

  const int tid  = threadIdx.x;
  const int wave = tid >> 6;
  const int lane = tid & 63;
  const int px   = lane & 31;     // pixel (C col)
  const int hi   = lane >> 5;

  const int wg     = blockIdx.x;
  const int bb     = wg >> 5;
  const int hwbase = (wg & 31) * 32;
  const float* xbase = xin + (size_t)bb * (CIN * HW) + hwbase + px;

  // ---- x into registers, GEMM1-C row layout, bf16 packed pairs (16 VGPRs) ----
  // c(ct,r) = (wave*2+ct)*32 + (r&3) + 8*(r>>2) + 4*hi ; pair q packs r=2q,2q+1
  unsigned x_pk[2][8];
#pragma unroll
  for (int ct = 0; ct < 2; ++ct)
#pragma unroll
    for (int q = 0; q < 8; ++q) {
      int c = (wave * 2 + ct) * 32 + 2 * (q & 1) + 8 * (q >> 1) + 4 * hi;
      x_pk[ct][q] = cvt_pk_bf16(xbase[c * HW], xbase[(c + 1) * HW]);
    }

  // ---- init hA = bf16(1/512) (exact) ----
  {
    unsigned* h32 = (unsigned*)hA;
#pragma unroll
    for (int g = 0; g < 32; ++g) h32[tid + (g << 8)] = 0x3B003B00u;  // two bf16(2^-9)
  }

  f32x16 hreg[4];   // j = (wave*4+jt)*32 + (r&3)+8*(r>>2)+4*hi , col = px
#pragma unroll
  for (int jt = 0; jt < 4; ++jt)
#pragma unroll
    for (int r = 0; r < 16; ++r) hreg[jt][r] = 1.0f / 512.0f;

  const unsigned short* w1w = w1 + (size_t)(wave * 2) * 32 * 512 + lane * 8;
  const unsigned short* w2w = w2 + (size_t)(wave * 4) * 16 * 512 + lane * 8;
  const unsigned short* hAr = hA + lane * 8;
  const unsigned short* yFr = yF + lane * 8;

  __syncthreads();

  for (int it = 0; it < ITERS; ++it) {
    // ===== Phase A: GEMM1 (swapped), split per ct: acc1 = 16 regs live =====
    // rec^T[c][px] = sum_j W[j][c] * h[px][j]
#pragma unroll
    for (int ct = 0; ct < 2; ++ct) {
      f32x16 acc1;
#pragma unroll
      for (int r = 0; r < 16; ++r) acc1[r] = 0.0f;
      const unsigned short* wp = w1w + ct * (32 * 512);
#pragma unroll 2
      for (int kt = 0; kt < 32; ++kt) {
        bf16x8 b = *(const bf16x8*)(hAr + kt * 512);
        bf16x8 a = *(const bf16x8*)(wp + kt * 512);
        acc1 = __builtin_amdgcn_mfma_f32_32x32x16_bf16(a, b, acc1, 0, 0, 0);
      }
      // y = x / (rec + 1e-20) -> yF (GEMM2 B-frag layout), single b64 stores
      // c = (wave*2+ct)*32 + 8*rb + 4*hi + t ; kt2=(wave*2+ct)*2+(rb>>1),
      // slot=((rb&1)<<5)+px, i=4*hi+t
#pragma unroll
      for (int rb = 0; rb < 4; ++rb) {
        unsigned xa = x_pk[ct][2 * rb], xb = x_pk[ct][2 * rb + 1];
        float x0 = __builtin_bit_cast(float, xa << 16);
        float x1 = __builtin_bit_cast(float, xa & 0xffff0000u);
        float x2 = __builtin_bit_cast(float, xb << 16);
        float x3 = __builtin_bit_cast(float, xb & 0xffff0000u);
        float y0 = x0 * __builtin_amdgcn_rcpf(acc1[4 * rb + 0] + 1e-20f);
        float y1 = x1 * __builtin_amdgcn_rcpf(acc1[4 * rb + 1] + 1e-20f);
        float y2 = x2 * __builtin_amdgcn_rcpf(acc1[4 * rb + 2] + 1e-20f);
        float y3 = x3 * __builtin_amdgcn_rcpf(acc1[4 * rb + 3] + 1e-20f);
        int kt2 = (wave * 2 + ct) * 2 + (rb >> 1);
        u32x2 pk = { cvt_pk_bf16(y0, y1), cvt_pk_bf16(y2, y3) };
        *(u32x2*)(yF + ((kt2 * 64 + ((rb & 1) << 5) + px) << 3) + (hi << 2)) = pk;
      }
    }
    __syncthreads();   // (a) yF complete

    // ===== Phase B: GEMM2 (swapped), split per jt-pair: acc2 = 32 regs live =====
    // t^T[j][px] = sum_c W[j][c] * y[px][c] ; fold into hreg immediately
    float psum = 0.0f;
#pragma unroll
    for (int h2 = 0; h2 < 2; ++h2) {
      f32x16 acc2[2];
#pragma unroll
      for (int n = 0; n < 2; ++n)
#pragma unroll
        for (int r = 0; r < 16; ++r) acc2[n][r] = 0.0f;
#pragma unroll 2
      for (int kt = 0; kt < 16; ++kt) {
        bf16x8 b  = *(const bf16x8*)(yFr + kt * 512);
        bf16x8 a0 = *(const bf16x8*)(w2w + (((h2 * 2 + 0) * 16) + kt) * 512);
        bf16x8 a1 = *(const bf16x8*)(w2w + (((h2 * 2 + 1) * 16) + kt) * 512);
        acc2[0] = __builtin_amdgcn_mfma_f32_32x32x16_bf16(a0, b, acc2[0], 0, 0, 0);
        acc2[1] = __builtin_amdgcn_mfma_f32_32x32x16_bf16(a1, b, acc2[1], 0, 0, 0);
      }
#pragma unroll
      for (int n = 0; n < 2; ++n)
#pragma unroll
        for (int r = 0; r < 16; ++r) {
          int jt = h2 * 2 + n;
          float hn = hreg[jt][r] * acc2[n][r];
          hreg[jt][r] = hn;
          psum += hn;
        }
    }

    // ===== per-pixel sum over all 512 j, normalize =====
    psum += __shfl_xor(psum, 32, 64);          // fold lane-hi halves (same px)
    if (lane < 32) red[lane * 4 + wave] = psum;
    __syncthreads();   // (b) red visible

    f32x4 p = *(const f32x4*)(red + px * 4);
    float inv = __builtin_amdgcn_rcpf(p[0] + p[1] + p[2] + p[3] + 1e-19f);

    if (it < ITERS - 1) {
      // normalize + restage h into hA (GEMM1 B-frag layout), single b64 stores
#pragma unroll
      for (int jt = 0; jt < 4; ++jt)
#pragma unroll
        for (int rb = 0; rb < 4; ++rb) {
          float h0 = hreg[jt][4 * rb + 0] * inv;
          float h1 = hreg[jt][4 * rb + 1] * inv;
          float h2v = hreg[jt][4 * rb + 2] * inv;
          float h3 = hreg[jt][4 * rb + 3] * inv;
          hreg[jt][4 * rb + 0] = h0; hreg[jt][4 * rb + 1] = h1;
          hreg[jt][4 * rb + 2] = h2v; hreg[jt][4 * rb + 3] = h3;
          int kt = (wave * 4 + jt) * 2 + (rb >> 1);
          u32x2 pk = { cvt_pk_bf16(h0, h1), cvt_pk_bf16(h2v, h3) };
          *(u32x2*)(hA + ((kt * 64 + ((rb & 1) << 5) + px) << 3) + (hi << 2)) = pk;
        }
    } else {
      // final store fp32: out[b][j][hw]; lanes 0..31 = consecutive px -> coalesced
      float* obase = out + (size_t)bb * (COUT * HW) + hwbase + px;
#pragma unroll
      for (int jt = 0; jt < 4; ++jt)
#pragma unroll
        for (int r = 0; r < 16; ++r) {
          int j = (wave * 4 + jt) * 32 + (r & 3) + 8 * (r >> 2) + 4 * hi;
          obase[j * HW] = hreg[jt][r] * inv;
        }
    }
    __syncthreads();   // (c) hA ready / yF & red reusable
  }
}

extern "C" void kernel_launch(void* const* d_in, const int* in_sizes, int n_in,
                              void* d_out, int out_size, void* d_ws, size_t ws_size,
                              hipStream_t stream) {
  const float* x = (const float*)d_in[0];   // [32,256,32,32]
  const float* w = (const float*)d_in[1];   // [512,256]
  unsigned short* w1 = (unsigned short*)d_ws;          // 256 KB
  unsigned short* w2 = w1 + COUT * CIN;                // 256 KB
  float* out = (float*)d_out;

  prep_weights<<<dim3(512), dim3(256), 0, stream>>>(w, w1, w2);
  nnmf_kernel<<<dim3(32768 / 32), dim3(256), 0, stream>>>(x, w1, w2, out);
}

// Round 4
// 578.746 us; speedup vs baseline: 2.0439x; 2.0439x over previous
//
#include <hip/hip_runtime.h>

#define CIN   256
#define COUT  512
#define HW    1024     // H*W = 32*32
#define ITERS 20

typedef __attribute__((ext_vector_type(8)))  short bf16x8;
typedef __attribute__((ext_vector_type(4)))  float f32x4;
typedef __attribute__((ext_vector_type(16))) float f32x16;
typedef __attribute__((ext_vector_type(2)))  unsigned u32x2;

__device__ __forceinline__ unsigned short f2b(float x) {
  unsigned b = __builtin_bit_cast(unsigned, x);
  unsigned r = (b + 0x7FFFu + ((b >> 16) & 1u)) >> 16;   // RNE
  return (unsigned short)r;
}
// packed f32x2 -> bf16x2 (RNE), lo = a, hi = b
__device__ __forceinline__ unsigned cvt_pk_bf16(float a, float b) {
  unsigned r;
  asm("v_cvt_pk_bf16_f32 %0, %1, %2" : "=v"(r) : "v"(a), "v"(b));
  return r;
}

// 32x32x16 MFMA fragment conventions (gfx950):
//  A-frag: lane l holds row m = l&31,  k = (l>>5)*8 + i  (i=0..7)
//  B-frag: lane l holds col n = l&31,  k = (l>>5)*8 + i
//  C/D   : col = lane&31, row = (r&3) + 8*(r>>2) + 4*(lane>>5), r in [0,16)
//
// Both GEMMs computed TRANSPOSED (A = weights, B = h/y, cols = pixels).
//
// w1: GEMM1 A-frags [ct:8][kt:32][lane:64][i:8];  c = ct*32+(l&31), j = kt*16+(l>>5)*8+i
// w2: GEMM2 A-frags [jt:16][kt:16][lane:64][i:8]; j = jt*32+(l&31), c = kt*16+(l>>5)*8+i
__global__ __launch_bounds__(256) void prep_weights(const float* __restrict__ w,
                                                    unsigned short* __restrict__ w1,
                                                    unsigned short* __restrict__ w2) {
  int f = blockIdx.x * 256 + threadIdx.x;   // [0, 131072)
  {
    int i = f & 7, l = (f >> 3) & 63, kt = (f >> 9) & 31, ct = f >> 14;
    int c = ct * 32 + (l & 31);
    int j = kt * 16 + ((l >> 5) << 3) + i;
    w1[f] = f2b(w[j * CIN + c]);
  }
  {
    int i = f & 7, l = (f >> 3) & 63, kt = (f >> 9) & 15, jt = f >> 13;
    int j = jt * 32 + (l & 31);
    int c = kt * 16 + ((l >> 5) << 3) + i;
    w2[f] = f2b(w[j * CIN + c]);
  }
}

// R4: 1 WG = 64 pixels (2 px-tiles), 8 waves of 512 threads, all 20 iters on-chip.
// Each wave owns BOTH px-tiles but 1/8 of channels: every weight A-frag load feeds
// TWO MFMAs -> global loads per MFMA and L2 weight traffic per pixel both halved
// (10.7 -> 5.4 GB over the kernel). GEMM1: 1 ct/wave (8 ct = 8 waves exactly).
// GEMM2: 2 jt/wave, sequential (acc2 = 32 live).
// __launch_bounds__(512,2) pins unified VGPR+AGPR <= 256 (R1: forcing lower = spill;
// R3: leaving it free = balloon to 1 wave/SIMD). Peak liveness ~170 -> no spill.
// LDS 98.3KB -> 1 block/CU, 2 waves/SIMD.
__global__ __launch_bounds__(512, 2) void nnmf_kernel(const float* __restrict__ xin,
                                                      const unsigned short* __restrict__ w1,
                                                      const unsigned short* __restrict__ w2,
                                                      float* __restrict__ out) {
  __shared__ __align__(16) unsigned short hA[2 * 32 * 512]; // 64KB  B-frags GEMM1 (k=j), per px-tile
  __shared__ __align__(16) unsigned short yF[2 * 16 * 512]; // 32KB  B-frags GEMM2 (k=c), per px-tile
  __shared__ float red[2 * 32 * 9];                         // 2304B per-(pt,px) partials, stride 9 = conflict-free

  const int tid  = threadIdx.x;
  const int wv   = tid >> 6;      // 0..7
  const int lane = tid & 63;
  const int px   = lane & 31;     // pixel within tile (C col)
  const int hi   = lane >> 5;

  const int wg     = blockIdx.x;       // 512 blocks
  const int bb     = wg >> 4;          // image
  const int hwbase = (wg & 15) * 64;   // 64 consecutive pixels
  const float* xbase = xin + (size_t)bb * (CIN * HW) + hwbase + px;

  // ---- x into registers, GEMM1-C row layout, bf16 packed pairs (16 VGPRs) ----
  // c(r) = wv*32 + (r&3) + 8*(r>>2) + 4*hi ; pair q packs r=2q,2q+1
  unsigned x_pk[2][8];
#pragma unroll
  for (int pt = 0; pt < 2; ++pt)
#pragma unroll
    for (int q = 0; q < 8; ++q) {
      int c = wv * 32 + 2 * (q & 1) + 8 * (q >> 1) + 4 * hi;
      x_pk[pt][q] = cvt_pk_bf16(xbase[c * HW + pt * 32], xbase[(c + 1) * HW + pt * 32]);
    }

  // ---- init hA = bf16(1/512) (exact): 16384 u32 words / 512 threads ----
  {
    unsigned* h32 = (unsigned*)hA;
#pragma unroll
    for (int g = 0; g < 32; ++g) h32[tid + (g << 9)] = 0x3B003B00u;  // two bf16(2^-9)
  }

  // persistent fp32 h: j = (wv*2+n)*32 + (r&3)+8*(r>>2)+4*hi, col = hwbase+pt*32+px
  f32x16 hreg[2][2];   // [n][pt]
#pragma unroll
  for (int n = 0; n < 2; ++n)
#pragma unroll
    for (int pt = 0; pt < 2; ++pt)
#pragma unroll
      for (int r = 0; r < 16; ++r) hreg[n][pt][r] = 1.0f / 512.0f;

  const unsigned short* w1w = w1 + (size_t)wv * (32 * 512) + lane * 8;       // ct = wv
  const unsigned short* w2w = w2 + (size_t)(wv * 2) * (16 * 512) + lane * 8; // jt = 2wv+n
  const unsigned short* hAr = hA + lane * 8;
  const unsigned short* yFr = yF + lane * 8;

  __syncthreads();

  for (int it = 0; it < ITERS; ++it) {
    // ===== Phase A: GEMM1 (swapped): rec^T[c][px] = sum_j W[j][c] h[px][j] =====
    // One weight A-frag load -> 2 MFMAs (px-tile 0 and 1). acc = 32 live.
    f32x16 acc1[2];
#pragma unroll
    for (int pt = 0; pt < 2; ++pt)
#pragma unroll
      for (int r = 0; r < 16; ++r) acc1[pt][r] = 0.0f;

#pragma unroll 2
    for (int kt = 0; kt < 32; ++kt) {
      bf16x8 a  = *(const bf16x8*)(w1w + kt * 512);
      bf16x8 b0 = *(const bf16x8*)(hAr + kt * 512);          // px-tile 0
      bf16x8 b1 = *(const bf16x8*)(hAr + (32 + kt) * 512);   // px-tile 1
      acc1[0] = __builtin_amdgcn_mfma_f32_32x32x16_bf16(a, b0, acc1[0], 0, 0, 0);
      acc1[1] = __builtin_amdgcn_mfma_f32_32x32x16_bf16(a, b1, acc1[1], 0, 0, 0);
    }

    // y = x / (rec + 1e-20) -> yF (GEMM2 B-frag layout), single b64 stores
    // c = wv*32 + 8*rb + 4*hi + t ; kt2 = wv*2 + (rb>>1); slot=((rb&1)<<5)+px; i=4*hi+t
#pragma unroll
    for (int pt = 0; pt < 2; ++pt)
#pragma unroll
      for (int rb = 0; rb < 4; ++rb) {
        unsigned xa = x_pk[pt][2 * rb], xb = x_pk[pt][2 * rb + 1];
        float x0 = __builtin_bit_cast(float, xa << 16);
        float x1 = __builtin_bit_cast(float, xa & 0xffff0000u);
        float x2 = __builtin_bit_cast(float, xb << 16);
        float x3 = __builtin_bit_cast(float, xb & 0xffff0000u);
        float y0 = x0 * __builtin_amdgcn_rcpf(acc1[pt][4 * rb + 0] + 1e-20f);
        float y1 = x1 * __builtin_amdgcn_rcpf(acc1[pt][4 * rb + 1] + 1e-20f);
        float y2 = x2 * __builtin_amdgcn_rcpf(acc1[pt][4 * rb + 2] + 1e-20f);
        float y3 = x3 * __builtin_amdgcn_rcpf(acc1[pt][4 * rb + 3] + 1e-20f);
        int kt2 = wv * 2 + (rb >> 1);
        u32x2 pk = { cvt_pk_bf16(y0, y1), cvt_pk_bf16(y2, y3) };
        *(u32x2*)(yF + (((pt * 16 + kt2) * 64 + ((rb & 1) << 5) + px) << 3) + (hi << 2)) = pk;
      }
    __syncthreads();   // (a) yF complete

    // ===== Phase B: GEMM2 (swapped): t^T[j][px] = sum_c W[j][c] y[px][c] =====
    // 2 jt sequential; per kt: 1 weight A-frag -> 2 MFMAs. acc = 32 live.
    float psum0 = 0.0f, psum1 = 0.0f;
#pragma unroll
    for (int n = 0; n < 2; ++n) {
      f32x16 acc2[2];
#pragma unroll
      for (int pt = 0; pt < 2; ++pt)
#pragma unroll
        for (int r = 0; r < 16; ++r) acc2[pt][r] = 0.0f;
#pragma unroll 2
      for (int kt = 0; kt < 16; ++kt) {
        bf16x8 a  = *(const bf16x8*)(w2w + (n * 16 + kt) * 512);
        bf16x8 b0 = *(const bf16x8*)(yFr + kt * 512);          // px-tile 0
        bf16x8 b1 = *(const bf16x8*)(yFr + (16 + kt) * 512);   // px-tile 1
        acc2[0] = __builtin_amdgcn_mfma_f32_32x32x16_bf16(a, b0, acc2[0], 0, 0, 0);
        acc2[1] = __builtin_amdgcn_mfma_f32_32x32x16_bf16(a, b1, acc2[1], 0, 0, 0);
      }
#pragma unroll
      for (int r = 0; r < 16; ++r) {
        float hn0 = hreg[n][0][r] * acc2[0][r];
        float hn1 = hreg[n][1][r] * acc2[1][r];
        hreg[n][0][r] = hn0;
        hreg[n][1][r] = hn1;
        psum0 += hn0;
        psum1 += hn1;
      }
    }

    // ===== per-(pt,px) sum over all 512 j, normalize =====
    psum0 += __shfl_xor(psum0, 32, 64);   // fold complementary row-half (same px)
    psum1 += __shfl_xor(psum1, 32, 64);
    if (lane < 32) {
      red[px * 9 + wv]        = psum0;
      red[(32 + px) * 9 + wv] = psum1;
    }
    __syncthreads();   // (b) red visible

    float s0 = 0.0f, s1 = 0.0f;
#pragma unroll
    for (int w8 = 0; w8 < 8; ++w8) {
      s0 += red[px * 9 + w8];
      s1 += red[(32 + px) * 9 + w8];
    }
    float inv[2];
    inv[0] = __builtin_amdgcn_rcpf(s0 + 1e-19f);
    inv[1] = __builtin_amdgcn_rcpf(s1 + 1e-19f);

    if (it < ITERS - 1) {
      // normalize + restage h into hA (GEMM1 B-frag layout), single b64 stores
      // j = (wv*2+n)*32 + 8*rb + 4*hi + t ; kt = (wv*2+n)*2+(rb>>1)
#pragma unroll
      for (int n = 0; n < 2; ++n)
#pragma unroll
        for (int pt = 0; pt < 2; ++pt)
#pragma unroll
          for (int rb = 0; rb < 4; ++rb) {
            float h0 = hreg[n][pt][4 * rb + 0] * inv[pt];
            float h1 = hreg[n][pt][4 * rb + 1] * inv[pt];
            float h2 = hreg[n][pt][4 * rb + 2] * inv[pt];
            float h3 = hreg[n][pt][4 * rb + 3] * inv[pt];
            hreg[n][pt][4 * rb + 0] = h0; hreg[n][pt][4 * rb + 1] = h1;
            hreg[n][pt][4 * rb + 2] = h2; hreg[n][pt][4 * rb + 3] = h3;
            int kt = (wv * 2 + n) * 2 + (rb >> 1);
            u32x2 pk = { cvt_pk_bf16(h0, h1), cvt_pk_bf16(h2, h3) };
            *(u32x2*)(hA + (((pt * 32 + kt) * 64 + ((rb & 1) << 5) + px) << 3) + (hi << 2)) = pk;
          }
    } else {
      // final store fp32: out[b][j][hw]; lanes = consecutive px -> coalesced
      float* obase = out + (size_t)bb * (COUT * HW) + hwbase + px;
#pragma unroll
      for (int n = 0; n < 2; ++n)
#pragma unroll
        for (int pt = 0; pt < 2; ++pt)
#pragma unroll
          for (int r = 0; r < 16; ++r) {
            int j = (wv * 2 + n) * 32 + (r & 3) + 8 * (r >> 2) + 4 * hi;
            obase[j * HW + pt * 32] = hreg[n][pt][r] * inv[pt];
          }
    }
    __syncthreads();   // (c) hA ready / yF & red reusable
  }
}

extern "C" void kernel_launch(void* const* d_in, const int* in_sizes, int n_in,
                              void* d_out, int out_size, void* d_ws, size_t ws_size,
                              hipStream_t stream) {
  const float* x = (const float*)d_in[0];   // [32,256,32,32]
  const float* w = (const float*)d_in[1];   // [512,256]
  unsigned short* w1 = (unsigned short*)d_ws;          // 256 KB
  unsigned short* w2 = w1 + COUT * CIN;                // 256 KB
  float* out = (float*)d_out;

  prep_weights<<<dim3(512), dim3(256), 0, stream>>>(w, w1, w2);
  nnmf_kernel<<<dim3(512), dim3(512), 0, stream>>>(x, w1, w2, out);
}